// Round 19
// baseline (240.687 us; speedup 1.0000x reference)
//
#include <hip/hip_runtime.h>
#include <hip/hip_bf16.h>
#include <stdint.h>

#define NROWS 131072
#define BM 128
#define NTILES (NROWS / BM)      // 1024
#define NK1 20
#define NK2 16
#define FSTR 1280
#define HSTR 1024
#define RING_OFF 131072          // h: [0,131072); ring: [131072,163840)
#define FEATS_OFF 1184768        // byte offset of packed feats in ws
#define FEATS_BYTES (167772160ull)

typedef __attribute__((ext_vector_type(8))) short bf16x8;
typedef __attribute__((ext_vector_type(4))) float f32x4;
typedef __attribute__((ext_vector_type(16))) float f32x16;
typedef __attribute__((ext_vector_type(4))) int i32x4;
typedef __attribute__((ext_vector_type(2))) unsigned int u32x2;

__device__ __forceinline__ unsigned f2bf(float x) {
    union { float f; unsigned u; } v; v.f = x;
    unsigned r = v.u + 0x7FFFu + ((v.u >> 16) & 1u);
    return r >> 16;
}

__device__ __forceinline__ unsigned pk2(float a, float b) {
    float2 t; t.x = a; t.y = b;
    __hip_bfloat162 h = __float22bfloat162_rn(t);
    union { __hip_bfloat162 h; unsigned u; } c; c.h = h;
    return c.u;
}

__device__ __forceinline__ void lds_barrier() {
    asm volatile("s_waitcnt lgkmcnt(0)" ::: "memory");
    __builtin_amdgcn_sched_barrier(0);
    __builtin_amdgcn_s_barrier();
}

// ---------------------------------------------------------------------------
// prep_kernel: W packing (mode 1 = 32x32 frag order, mode 0 = 16x16) + tables
// ---------------------------------------------------------------------------
__global__ void prep_kernel(
    const float* __restrict__ W1, const float* __restrict__ W2,
    const float* __restrict__ Wsx, const float* __restrict__ bsx,
    const float* __restrict__ Wcx, const float* __restrict__ bcx,
    const float* __restrict__ Wsy, const float* __restrict__ bsy,
    const float* __restrict__ Wcy, const float* __restrict__ bcy,
    const float* __restrict__ Wn, const float* __restrict__ bn,
    unsigned short* __restrict__ w1bp, unsigned short* __restrict__ w2bp,
    float* __restrict__ wf, float* __restrict__ bfv, int mode)
{
    int i = blockIdx.x * blockDim.x + threadIdx.x;
    const int n1 = 512 * 640;
    const int n2 = 512 * 512;
    if (i < n1) {
        int e = i & 7, g = i >> 3;
        int lane = g & 63;
        int col, k;
        if (mode) {  // 32x32x16 A-frag: row=lane&31, k=(lane>>5)*8+e
            int s  = (g >> 6) & 1;
            int cn = (g >> 7) & 1;
            int wk = g >> 8;
            int ks = wk % 20, wv = wk / 20;
            col = wv * 64 + cn * 32 + (lane & 31);
            k   = ks * 32 + s * 16 + (lane >> 5) * 8 + e;
        } else {     // 16x16x32 A-frag
            int cf = (g >> 6) & 3;
            int wk = g >> 8;
            int ks = wk % 20, wv = wk / 20;
            col = wv * 64 + cf * 16 + (lane & 15);
            k   = ks * 32 + (lane >> 4) * 8 + e;
        }
        w1bp[i] = (unsigned short)f2bf(W1[col * 640 + k]);
    } else if (i < n1 + n2) {
        int ii = i - n1;
        int e = ii & 7, g = ii >> 3;
        int lane = g & 63;
        int col, k;
        if (mode) {
            int s  = (g >> 6) & 1;
            int cn = (g >> 7) & 1;
            int ks = (g >> 8) & 15, wv = g >> 12;
            col = wv * 64 + cn * 32 + (lane & 31);
            k   = ks * 32 + s * 16 + (lane >> 5) * 8 + e;
        } else {
            int cf = (g >> 6) & 3;
            int ks = (g >> 8) & 15, wv = g >> 12;
            col = wv * 64 + cf * 16 + (lane & 15);
            k   = ks * 32 + (lane >> 4) * 8 + e;
        }
        w2bp[ii] = (unsigned short)f2bf(W2[col * 512 + k]);
    }
    if (i < 640) {
        const float HPI = 1.57079632679489662f;
        const float INV2PI = 0.15915494309189535f;
        float w, b;
        if (i < 512) {
            int j = i & 63, q = (i >> 6) & 3;
            if      (q == 0) { w = Wsx[j]; b = bsx[j]; }
            else if (q == 1) { w = Wcx[j]; b = bcx[j] + HPI; }
            else if (q == 2) { w = Wsy[j]; b = bsy[j]; }
            else             { w = Wcy[j]; b = bcy[j] + HPI; }
            w *= INV2PI; b *= INV2PI;    // revolutions for raw v_sin_f32
        } else { w = Wn[i - 512]; b = bn[i - 512]; }
        wf[i] = w; bfv[i] = b;
    }
}

// ---------------------------------------------------------------------------
// prep_feats: all feats -> ws, packed per tile as the unit-major LDS image:
//   addr = FEATS + tile*163840 + (ku*128 + row)*16,  ku = k/8 in [0,80)
// grid dim3(40, NTILES), 256 threads; id_in_tile = bx*256+tid in [0,10240)
// ---------------------------------------------------------------------------
__global__ void prep_feats(
    const float* __restrict__ pf, const float* __restrict__ pt,
    const float* __restrict__ nm,
    const float* __restrict__ wf, const float* __restrict__ bfv,
    unsigned short* __restrict__ featsP)
{
    const int idt = blockIdx.x * 256 + threadIdx.x;   // 0..10239
    const int row = idt & 127;
    const int ku  = idt >> 7;                         // 0..79
    const int tile = blockIdx.y;
    const int grow = tile * 128 + row;
    const int k = ku * 8;

    const float xv = (ku < 16) ? pf[grow * 2 + 0] :
                     (ku < 32) ? pf[grow * 2 + 1] :
                     (ku < 48) ? pt[grow * 2 + 0] :
                     (ku < 64) ? pt[grow * 2 + 1] : nm[grow];

    const f32x4 w0 = *(const f32x4*)(wf + k);
    const f32x4 w1v = *(const f32x4*)(wf + k + 4);
    const f32x4 c0 = *(const f32x4*)(bfv + k);
    const f32x4 c1 = *(const f32x4*)(bfv + k + 4);
    float r[8];
    #pragma unroll
    for (int t = 0; t < 4; ++t) {
        float a0 = fmaf(xv, w0[t], c0[t]);
        float a1 = fmaf(xv, w1v[t], c1[t]);
        if (ku < 64) {
            asm("v_sin_f32 %0, %1" : "=v"(r[t])     : "v"(a0));
            asm("v_sin_f32 %0, %1" : "=v"(r[t + 4]) : "v"(a1));
        } else { r[t] = a0; r[t + 4] = a1; }
    }
    i32x4 pk;
    pk.x = (int)pk2(r[0], r[1]);
    pk.y = (int)pk2(r[2], r[3]);
    pk.z = (int)pk2(r[4], r[5]);
    pk.w = (int)pk2(r[6], r[7]);
    *(i32x4*)(featsP + (size_t)tile * 81920 + (size_t)(ku * 128 + row) * 8) = pk;
}

// ---------------------------------------------------------------------------
// mlp2: pure double-GEMM. feats streamed HBM->LDS via global_load_lds ring
// (4 slices x 8KB), counted vmcnt; h in LDS; 32x32x16 MFMA throughout.
// ---------------------------------------------------------------------------
__global__ __launch_bounds__(512, 2) void mlp2_kernel(
    const unsigned short* __restrict__ featsP,
    const unsigned short* __restrict__ w1bp,
    const unsigned short* __restrict__ w2bp,
    const float* __restrict__ b1, const float* __restrict__ b2,
    float* __restrict__ out)
{
    __shared__ __align__(16) unsigned char lds[163840];

    const int tid  = threadIdx.x;
    const int lane = tid & 63;
    const int wave = tid >> 6;
    const int l31  = lane & 31;
    const int l32  = lane >> 5;
    const int rowbase = blockIdx.x * BM;
    const int wcol = wave * 64;

    const unsigned short* w1p = w1bp + wave * (NK1 * 4 * 512) + lane * 8;
    const unsigned short* w2p = w2bp + wave * (NK2 * 4 * 512) + lane * 8;
#define W1F2(KS, CN, S) (*(const bf16x8*)(w1p + (((KS) * 4 + (CN) * 2 + (S)) * 512)))
#define W2F2(KS, CN, S) (*(const bf16x8*)(w2p + (((KS) * 4 + (CN) * 2 + (S)) * 512)))
// GEMM1 B-frag from ring slice (ks&3): u_local = s*2+l32, row = rn*32+l31
#define LDS_F1(KS, S, RN) (*(const bf16x8*)(lds + RING_OFF + ((KS) & 3) * 8192 + \
        (((((S) * 2 + l32) * 128) + (RN) * 32 + l31) << 4)))
// GEMM2 B-frag from h at base 0: unit = ks*4 + s*2 + l32
#define LDS_H2(KS, S, RN) (*(const bf16x8*)(lds + \
        (((((KS) * 4 + (S) * 2 + l32) * 128) + (RN) * 32 + l31) << 4)))

    const unsigned short* tileP = featsP + (size_t)blockIdx.x * 81920;

#define STAGE(KS) do {                                                             \
        __builtin_amdgcn_global_load_lds(                                          \
            (const __attribute__((address_space(1))) unsigned int*)                \
                (tileP + (KS) * 4096 + tid * 8),                                   \
            (__attribute__((address_space(3))) unsigned int*)                      \
                (lds + RING_OFF + ((KS) & 3) * 8192 + wave * 1024),                \
            16, 0, 0);                                                             \
    } while (0)

    // prologue: 3 slices in flight, then W preload for ks 0,1
    STAGE(0); STAGE(1); STAGE(2);

    bf16x8 wb[2][2][2];
    #pragma unroll
    for (int p = 0; p < 2; ++p)
        #pragma unroll
        for (int cn = 0; cn < 2; ++cn)
            #pragma unroll
            for (int s = 0; s < 2; ++s)
                wb[p][cn][s] = W1F2(p, cn, s);

    f32x16 acc[4][2];
    #pragma unroll
    for (int a = 0; a < 4; ++a)
        #pragma unroll
        for (int b = 0; b < 2; ++b) acc[a][b] = (f32x16)(0.0f);

    // -------- layer 1: K=640, ring-staged feats, counted vmcnt --------
    #pragma unroll
    for (int ks = 0; ks < NK1; ++ks) {
        // definite-newer-than-stage(ks) ops: stages {ks+1,ks+2}<20 + 8 W loads
        if (ks <= 17)      asm volatile("s_waitcnt vmcnt(10)" ::: "memory");
        else if (ks == 18) asm volatile("s_waitcnt vmcnt(9)"  ::: "memory");
        else               asm volatile("s_waitcnt vmcnt(8)"  ::: "memory");
        lds_barrier();
        if (ks + 3 < NK1) STAGE(ks + 3);
        const int cur = ks & 1;
        __builtin_amdgcn_s_setprio(1);
        #pragma unroll
        for (int s = 0; s < 2; ++s) {
            #pragma unroll
            for (int rn = 0; rn < 4; ++rn) {
                bf16x8 af = LDS_F1(ks, s, rn);
                #pragma unroll
                for (int cn = 0; cn < 2; ++cn)
                    acc[rn][cn] = __builtin_amdgcn_mfma_f32_32x32x16_bf16(
                        wb[cur][cn][s], af, acc[rn][cn], 0, 0, 0);
            }
        }
        __builtin_amdgcn_s_setprio(0);
        if (ks + 2 < NK1) {
            #pragma unroll
            for (int cn = 0; cn < 2; ++cn)
                #pragma unroll
                for (int s = 0; s < 2; ++s)
                    wb[cur][cn][s] = W1F2(ks + 2, cn, s);
        } else {
            #pragma unroll
            for (int cn = 0; cn < 2; ++cn)
                #pragma unroll
                for (int s = 0; s < 2; ++s)
                    wb[cur][cn][s] = W2F2(ks + 2 - NK1, cn, s);
        }
    }

    // -------- bias + leaky -> h (unit-major at base 0; disjoint from ring) ----
    #pragma unroll
    for (int rn = 0; rn < 4; ++rn) {
        const int row = rn * 32 + l31;
        #pragma unroll
        for (int cn = 0; cn < 2; ++cn) {
            #pragma unroll
            for (int rg = 0; rg < 4; ++rg) {
                const int colb = wcol + cn * 32 + rg * 8 + l32 * 4;
                const f32x4 bb = *(const f32x4*)(b1 + colb);
                float h0 = acc[rn][cn][rg * 4 + 0] + bb[0];
                float h1 = acc[rn][cn][rg * 4 + 1] + bb[1];
                float h2 = acc[rn][cn][rg * 4 + 2] + bb[2];
                float h3 = acc[rn][cn][rg * 4 + 3] + bb[3];
                h0 = (h0 >= 0.f) ? h0 : 0.01f * h0;
                h1 = (h1 >= 0.f) ? h1 : 0.01f * h1;
                h2 = (h2 >= 0.f) ? h2 : 0.01f * h2;
                h3 = (h3 >= 0.f) ? h3 : 0.01f * h3;
                u32x2 pk;
                pk.x = pk2(h0, h1);
                pk.y = pk2(h2, h3);
                const int ku = wave * 8 + cn * 4 + rg;
                *(u32x2*)(lds + ((ku * 128 + row) << 4) + l32 * 8) = pk;
            }
        }
    }

    #pragma unroll
    for (int a = 0; a < 4; ++a)
        #pragma unroll
        for (int b = 0; b < 2; ++b) acc[a][b] = (f32x16)(0.0f);

    lds_barrier();   // h visible

    // -------- layer 2: K=512 from LDS --------
    #pragma unroll
    for (int ks = 0; ks < NK2; ++ks) {
        const int cur = ks & 1;
        __builtin_amdgcn_s_setprio(1);
        #pragma unroll
        for (int s = 0; s < 2; ++s) {
            #pragma unroll
            for (int rn = 0; rn < 4; ++rn) {
                bf16x8 hf = LDS_H2(ks, s, rn);
                #pragma unroll
                for (int cn = 0; cn < 2; ++cn)
                    acc[rn][cn] = __builtin_amdgcn_mfma_f32_32x32x16_bf16(
                        wb[cur][cn][s], hf, acc[rn][cn], 0, 0, 0);
            }
        }
        __builtin_amdgcn_s_setprio(0);
        if (ks + 2 < NK2) {
            #pragma unroll
            for (int cn = 0; cn < 2; ++cn)
                #pragma unroll
                for (int s = 0; s < 2; ++s)
                    wb[cur][cn][s] = W2F2(ks + 2, cn, s);
        }
    }

    // -------- epilogue: bias + float4 stores --------
    #pragma unroll
    for (int rn = 0; rn < 4; ++rn) {
        const int row = rowbase + rn * 32 + l31;
        #pragma unroll
        for (int cn = 0; cn < 2; ++cn) {
            #pragma unroll
            for (int rg = 0; rg < 4; ++rg) {
                const int colb = wcol + cn * 32 + rg * 8 + l32 * 4;
                const f32x4 bb = *(const f32x4*)(b2 + colb);
                f32x4 o;
                o.x = acc[rn][cn][rg * 4 + 0] + bb[0];
                o.y = acc[rn][cn][rg * 4 + 1] + bb[1];
                o.z = acc[rn][cn][rg * 4 + 2] + bb[2];
                o.w = acc[rn][cn][rg * 4 + 3] + bb[3];
                *(f32x4*)(out + row * 512 + colb) = o;
            }
        }
    }
}

// ---------------------------------------------------------------------------
// mlp_fb: R15 kernel verbatim (16x16, fused encode) — fallback if ws too small
// ---------------------------------------------------------------------------
__global__ __launch_bounds__(512, 2) void mlp_fb_kernel(
    const float* __restrict__ pf, const float* __restrict__ pt,
    const float* __restrict__ nm,
    const unsigned short* __restrict__ w1bp,
    const unsigned short* __restrict__ w2bp,
    const float* __restrict__ wf, const float* __restrict__ bfv,
    const float* __restrict__ b1, const float* __restrict__ b2,
    float* __restrict__ out)
{
    __shared__ __align__(16) unsigned char lds[163840];

    const int tid  = threadIdx.x;
    const int lane = tid & 63;
    const int wave = tid >> 6;
    const int l15  = lane & 15;
    const int l4   = lane >> 4;
    const int rowbase = blockIdx.x * BM;
    const int wcol = wave * 64;
    const unsigned swz = (unsigned)(l15 << 4);

    const int erow = tid >> 2;
    const int esub = tid & 3;
    const int grow = rowbase + erow;
    const float v0 = pf[grow * 2 + 0];
    const float v1 = pf[grow * 2 + 1];
    const float v2 = pt[grow * 2 + 0];
    const float v3 = pt[grow * 2 + 1];
    const float v4 = nm[grow];

    const unsigned short* w1p = w1bp + wave * (NK1 * 4 * 512) + lane * 8;
    const unsigned short* w2p = w2bp + wave * (NK2 * 4 * 512) + lane * 8;
#define FBW1(KS, CF) (*(const bf16x8*)(w1p + ((KS) * 4 + (CF)) * 512))
#define FBW2(KS, CF) (*(const bf16x8*)(w2p + ((KS) * 4 + (CF)) * 512))
#define FB_AF(KS, RF) (*(const bf16x8*)(lds + ((RF) * 16 + l15) * FSTR + \
                        (((unsigned)((KS) * 64 + l4 * 16)) ^ swz)))
#define FB_HF(KS, RF) (*(const bf16x8*)(lds + ((RF) * 16 + l15) * HSTR + \
                        (((unsigned)((KS) * 64 + l4 * 16)) ^ swz)))

    bf16x8 wb[2][4];
    #pragma unroll
    for (int p = 0; p < 2; ++p)
        #pragma unroll
        for (int cf = 0; cf < 4; ++cf)
            wb[p][cf] = FBW1(p, cf);

    {
        const unsigned eswz = (unsigned)((erow & 15) << 4);
        #pragma unroll
        for (int j = 0; j < 20; ++j) {
            const int k = esub * 8 + j * 32;
            const float xv = (j < 4) ? v0 : (j < 8) ? v1 :
                             (j < 12) ? v2 : (j < 16) ? v3 : v4;
            const f32x4 w0 = *(const f32x4*)(wf + k);
            const f32x4 w1v = *(const f32x4*)(wf + k + 4);
            const f32x4 c0 = *(const f32x4*)(bfv + k);
            const f32x4 c1 = *(const f32x4*)(bfv + k + 4);
            float r[8];
            #pragma unroll
            for (int t = 0; t < 4; ++t) {
                float a0 = fmaf(xv, w0[t], c0[t]);
                float a1 = fmaf(xv, w1v[t], c1[t]);
                if (j < 16) {
                    asm("v_sin_f32 %0, %1" : "=v"(r[t])     : "v"(a0));
                    asm("v_sin_f32 %0, %1" : "=v"(r[t + 4]) : "v"(a1));
                } else { r[t] = a0; r[t + 4] = a1; }
            }
            i32x4 pk;
            pk.x = (int)pk2(r[0], r[1]);
            pk.y = (int)pk2(r[2], r[3]);
            pk.z = (int)pk2(r[4], r[5]);
            pk.w = (int)pk2(r[6], r[7]);
            *(i32x4*)(lds + erow * FSTR + (((unsigned)(k * 2)) ^ eswz)) = pk;
        }
    }

    f32x4 acc[8][4];
    #pragma unroll
    for (int a = 0; a < 8; ++a)
        #pragma unroll
        for (int b = 0; b < 4; ++b) acc[a][b] = (f32x4)(0.0f);

    lds_barrier();

    #pragma unroll
    for (int ks = 0; ks < NK1; ++ks) {
        const int cur = ks & 1;
        __builtin_amdgcn_s_setprio(1);
        #pragma unroll
        for (int rf = 0; rf < 8; ++rf) {
            bf16x8 af = FB_AF(ks, rf);
            #pragma unroll
            for (int cf = 0; cf < 4; ++cf)
                acc[rf][cf] = __builtin_amdgcn_mfma_f32_16x16x32_bf16(
                    wb[cur][cf], af, acc[rf][cf], 0, 0, 0);
        }
        __builtin_amdgcn_s_setprio(0);
        if (ks + 2 < NK1) {
            #pragma unroll
            for (int cf = 0; cf < 4; ++cf) wb[cur][cf] = FBW1(ks + 2, cf);
        } else {
            #pragma unroll
            for (int cf = 0; cf < 4; ++cf) wb[cur][cf] = FBW2(ks + 2 - NK1, cf);
        }
    }

    lds_barrier();

    #pragma unroll
    for (int cf = 0; cf < 4; ++cf) {
        const int colb = wcol + cf * 16 + l4 * 4;
        const f32x4 bb = *(const f32x4*)(b1 + colb);
        #pragma unroll
        for (int rf = 0; rf < 8; ++rf) {
            const int row = rf * 16 + l15;
            float h0 = acc[rf][cf][0] + bb[0];
            float h1 = acc[rf][cf][1] + bb[1];
            float h2 = acc[rf][cf][2] + bb[2];
            float h3 = acc[rf][cf][3] + bb[3];
            h0 = (h0 >= 0.f) ? h0 : 0.01f * h0;
            h1 = (h1 >= 0.f) ? h1 : 0.01f * h1;
            h2 = (h2 >= 0.f) ? h2 : 0.01f * h2;
            h3 = (h3 >= 0.f) ? h3 : 0.01f * h3;
            u32x2 pk;
            pk.x = pk2(h0, h1);
            pk.y = pk2(h2, h3);
            *(u32x2*)(lds + row * HSTR + (((unsigned)(colb * 2)) ^ swz)) = pk;
        }
    }

    #pragma unroll
    for (int a = 0; a < 8; ++a)
        #pragma unroll
        for (int b = 0; b < 4; ++b) acc[a][b] = (f32x4)(0.0f);

    lds_barrier();

    #pragma unroll
    for (int ks = 0; ks < NK2; ++ks) {
        const int cur = ks & 1;
        __builtin_amdgcn_s_setprio(1);
        #pragma unroll
        for (int rf = 0; rf < 8; ++rf) {
            bf16x8 hf = FB_HF(ks, rf);
            #pragma unroll
            for (int cf = 0; cf < 4; ++cf)
                acc[rf][cf] = __builtin_amdgcn_mfma_f32_16x16x32_bf16(
                    wb[cur][cf], hf, acc[rf][cf], 0, 0, 0);
        }
        __builtin_amdgcn_s_setprio(0);
        if (ks + 2 < NK2) {
            #pragma unroll
            for (int cf = 0; cf < 4; ++cf) wb[cur][cf] = FBW2(ks + 2, cf);
        }
    }

    #pragma unroll
    for (int cf = 0; cf < 4; ++cf) {
        const int colb = wcol + cf * 16 + l4 * 4;
        const f32x4 bb = *(const f32x4*)(b2 + colb);
        #pragma unroll
        for (int rf = 0; rf < 8; ++rf) {
            const int row = rowbase + rf * 16 + l15;
            f32x4 o = acc[rf][cf] + bb;
            *(f32x4*)(out + row * 512 + colb) = o;
        }
    }
}

extern "C" void kernel_launch(void* const* d_in, const int* in_sizes, int n_in,
                              void* d_out, int out_size, void* d_ws, size_t ws_size,
                              hipStream_t stream)
{
    (void)in_sizes; (void)n_in; (void)out_size;
    const float* pf  = (const float*)d_in[0];
    const float* pt  = (const float*)d_in[1];
    const float* nm  = (const float*)d_in[2];
    const float* Wsx = (const float*)d_in[3];
    const float* bsx = (const float*)d_in[4];
    const float* Wcx = (const float*)d_in[5];
    const float* bcx = (const float*)d_in[6];
    const float* Wsy = (const float*)d_in[7];
    const float* bsy = (const float*)d_in[8];
    const float* Wcy = (const float*)d_in[9];
    const float* bcy = (const float*)d_in[10];
    const float* Wn  = (const float*)d_in[11];
    const float* bn  = (const float*)d_in[12];
    const float* W1  = (const float*)d_in[13];
    const float* b1  = (const float*)d_in[14];
    const float* W2  = (const float*)d_in[15];
    const float* b2  = (const float*)d_in[16];

    unsigned char* ws = (unsigned char*)d_ws;
    unsigned short* w1bp = (unsigned short*)(ws);
    unsigned short* w2bp = (unsigned short*)(ws + 512 * 640 * 2);
    float* wf  = (float*)(ws + 512 * 640 * 2 + 512 * 512 * 2);
    float* bfv = (float*)(ws + 512 * 640 * 2 + 512 * 512 * 2 + 640 * 4);

    const bool big = ws_size >= (size_t)FEATS_OFF + FEATS_BYTES;
    const int prep_threads = 512 * 640 + 512 * 512;
    prep_kernel<<<(prep_threads + 255) / 256, 256, 0, stream>>>(
        W1, W2, Wsx, bsx, Wcx, bcx, Wsy, bsy, Wcy, bcy, Wn, bn,
        w1bp, w2bp, wf, bfv, big ? 1 : 0);

    if (big) {
        unsigned short* featsP = (unsigned short*)(ws + FEATS_OFF);
        prep_feats<<<dim3(40, NTILES), 256, 0, stream>>>(pf, pt, nm, wf, bfv, featsP);
        mlp2_kernel<<<NTILES, 512, 0, stream>>>(featsP, w1bp, w2bp, b1, b2, (float*)d_out);
    } else {
        mlp_fb_kernel<<<NROWS / BM, 512, 0, stream>>>(
            pf, pt, nm, w1bp, w2bp, wf, bfv, b1, b2, (float*)d_out);
    }
}

// Round 20
// 215.352 us; speedup vs baseline: 1.1176x; 1.1176x over previous
//
#include <hip/hip_runtime.h>
#include <hip/hip_bf16.h>
#include <stdint.h>

#define NROWS 131072
#define BM 64
#define NK1 20
#define NK2 16

typedef __attribute__((ext_vector_type(8))) short bf16x8;
typedef __attribute__((ext_vector_type(4))) float f32x4;
typedef __attribute__((ext_vector_type(16))) float f32x16;
typedef __attribute__((ext_vector_type(4))) int i32x4;
typedef __attribute__((ext_vector_type(2))) unsigned int u32x2;

__device__ __forceinline__ unsigned f2bf(float x) {
    union { float f; unsigned u; } v; v.f = x;
    unsigned r = v.u + 0x7FFFu + ((v.u >> 16) & 1u);
    return r >> 16;
}

__device__ __forceinline__ unsigned pk2(float a, float b) {
    float2 t; t.x = a; t.y = b;
    __hip_bfloat162 h = __float22bfloat162_rn(t);
    union { __hip_bfloat162 h; unsigned u; } c; c.h = h;
    return c.u;
}

__device__ __forceinline__ void lds_barrier() {
    asm volatile("s_waitcnt lgkmcnt(0)" ::: "memory");
    __builtin_amdgcn_sched_barrier(0);
    __builtin_amdgcn_s_barrier();
}

// ws layout (32x32x16 A-frag packing, same as R17/R18):
// [0, 655360)            W1 bf16 PACKED [wv8][ks20][cn2][s2][lane64][8]
// [655360, 1179648)      W2 bf16 PACKED [wv8][ks16][cn2][s2][lane64][8]
// [1179648, +2560)       wf[640] f32 (trig rows pre-scaled by 1/2pi)
// [1182208, +2560)       bfv[640] f32 (cos folded to sin, pre-scaled)

__global__ void prep_kernel(
    const float* __restrict__ W1, const float* __restrict__ W2,
    const float* __restrict__ Wsx, const float* __restrict__ bsx,
    const float* __restrict__ Wcx, const float* __restrict__ bcx,
    const float* __restrict__ Wsy, const float* __restrict__ bsy,
    const float* __restrict__ Wcy, const float* __restrict__ bcy,
    const float* __restrict__ Wn, const float* __restrict__ bn,
    unsigned short* __restrict__ w1bp, unsigned short* __restrict__ w2bp,
    float* __restrict__ wf, float* __restrict__ bfv)
{
    int i = blockIdx.x * blockDim.x + threadIdx.x;
    const int n1 = 512 * 640;
    const int n2 = 512 * 512;
    if (i < n1) {
        int e = i & 7, g = i >> 3;
        int lane = g & 63;
        int s  = (g >> 6) & 1;
        int cn = (g >> 7) & 1;
        int wk = g >> 8;                 // wv*20 + ks
        int ks = wk % 20, wv = wk / 20;
        int col = wv * 64 + cn * 32 + (lane & 31);
        int k   = ks * 32 + s * 16 + (lane >> 5) * 8 + e;
        w1bp[i] = (unsigned short)f2bf(W1[col * 640 + k]);
    } else if (i < n1 + n2) {
        int ii = i - n1;
        int e = ii & 7, g = ii >> 3;
        int lane = g & 63;
        int s  = (g >> 6) & 1;
        int cn = (g >> 7) & 1;
        int ks = (g >> 8) & 15, wv = g >> 12;
        int col = wv * 64 + cn * 32 + (lane & 31);
        int k   = ks * 32 + s * 16 + (lane >> 5) * 8 + e;
        w2bp[ii] = (unsigned short)f2bf(W2[col * 512 + k]);
    }
    if (i < 640) {
        const float HPI = 1.57079632679489662f;
        const float INV2PI = 0.15915494309189535f;
        float w, b;
        if (i < 512) {
            int j = i & 63, q = (i >> 6) & 3;
            if      (q == 0) { w = Wsx[j]; b = bsx[j]; }
            else if (q == 1) { w = Wcx[j]; b = bcx[j] + HPI; }
            else if (q == 2) { w = Wsy[j]; b = bsy[j]; }
            else             { w = Wcy[j]; b = bcy[j] + HPI; }
            w *= INV2PI; b *= INV2PI;    // revolutions for raw v_sin_f32
        } else { w = Wn[i - 512]; b = bn[i - 512]; }
        wf[i] = w; bfv[i] = b;
    }
}

// 256 threads = 4 waves, BM=64; wave w owns cols w*128..+127 (cnp 0..3 x 32).
// LDS unit-major: feats ku in [0,80), addr=(ku*64+row)*16 -> 81920 B (2 blk/CU)
// h aliased at base, ku in [0,64).

__global__ __launch_bounds__(256, 2) void mlp_kernel(
    const float* __restrict__ pf, const float* __restrict__ pt,
    const float* __restrict__ nm,
    const unsigned short* __restrict__ w1bp,
    const unsigned short* __restrict__ w2bp,
    const float* __restrict__ wf, const float* __restrict__ bfv,
    const float* __restrict__ b1, const float* __restrict__ b2,
    float* __restrict__ out)
{
    __shared__ __align__(16) unsigned char lds[81920];

    const int tid  = threadIdx.x;
    const int lane = tid & 63;
    const int wave = tid >> 6;          // 0..3, each owns 128 output cols
    const int l31  = lane & 31;
    const int l32  = lane >> 5;         // 0..1
    const int rowbase = blockIdx.x * BM;
    const int wcol = wave * 128;

    // one-time de-phase: delay one block of each co-resident pair ~7us.
    // s=(bid>>3) strips XCD round-robin; (s^(s>>5))&1 separates pairs under
    // both plausible slot-fill orders (k,k+1) and (k,k+32).
    {
        unsigned sb = (unsigned)blockIdx.x >> 3;
        if (((sb ^ (sb >> 5)) & 1u) != 0u) {
            __builtin_amdgcn_s_sleep(127);
            __builtin_amdgcn_s_sleep(127);
            __builtin_amdgcn_s_sleep(127);
            __builtin_amdgcn_s_sleep(127);
            __builtin_amdgcn_s_sleep(127);
        }
    }

    // encode mapping: 4 threads/row
    const int erow = tid >> 2;          // 0..63
    const int esub = tid & 3;
    const int grow = rowbase + erow;
    const float v0 = pf[grow * 2 + 0];
    const float v1 = pf[grow * 2 + 1];
    const float v2 = pt[grow * 2 + 0];
    const float v3 = pt[grow * 2 + 1];
    const float v4 = nm[grow];

    // packed W streams: wave covers wv slices {2w, 2w+1}; cnp<2 -> slice a
    const unsigned short* w1pa = w1bp + (wave * 2 + 0) * (NK1 * 4 * 512) + lane * 8;
    const unsigned short* w1pb = w1bp + (wave * 2 + 1) * (NK1 * 4 * 512) + lane * 8;
    const unsigned short* w2pa = w2bp + (wave * 2 + 0) * (NK2 * 4 * 512) + lane * 8;
    const unsigned short* w2pb = w2bp + (wave * 2 + 1) * (NK2 * 4 * 512) + lane * 8;
#define W1FR(KS, CNP, S) (*(const bf16x8*)(((CNP) < 2 ? w1pa : w1pb) + \
        ((KS) * 4 + ((CNP) & 1) * 2 + (S)) * 512))
#define W2FR(KS, CNP, S) (*(const bf16x8*)(((CNP) < 2 ? w2pa : w2pb) + \
        ((KS) * 4 + ((CNP) & 1) * 2 + (S)) * 512))
#define LDS_BF(KS, S, RN) (*(const bf16x8*)(lds + \
        ((((KS) * 4 + (S) * 2 + l32) * 64 + (RN) * 32 + l31) << 4)))

    // ---------------- encode: k = esub*8 + j*32, ku = esub + j*4 ----------------
    // segment per j compile-time: j0-3 pf.x | j4-7 pf.y | j8-11 pt.x |
    // j12-15 pt.y | j16-19 numbers ; native v_sin for j<16 (pre-scaled).
    {
        #pragma unroll
        for (int j = 0; j < 20; ++j) {
            const int k = esub * 8 + j * 32;
            const int ku = esub + j * 4;
            const float xv = (j < 4) ? v0 : (j < 8) ? v1 :
                             (j < 12) ? v2 : (j < 16) ? v3 : v4;
            const f32x4 w0 = *(const f32x4*)(wf + k);
            const f32x4 w1v = *(const f32x4*)(wf + k + 4);
            const f32x4 c0 = *(const f32x4*)(bfv + k);
            const f32x4 c1 = *(const f32x4*)(bfv + k + 4);
            float r[8];
            #pragma unroll
            for (int t = 0; t < 4; ++t) {
                float a0 = fmaf(xv, w0[t], c0[t]);
                float a1 = fmaf(xv, w1v[t], c1[t]);
                if (j < 16) {
                    asm("v_sin_f32 %0, %1" : "=v"(r[t])     : "v"(a0));
                    asm("v_sin_f32 %0, %1" : "=v"(r[t + 4]) : "v"(a1));
                } else { r[t] = a0; r[t + 4] = a1; }
            }
            i32x4 pk;
            pk.x = (int)pk2(r[0], r[1]);
            pk.y = (int)pk2(r[2], r[3]);
            pk.z = (int)pk2(r[4], r[5]);
            pk.w = (int)pk2(r[6], r[7]);
            *(i32x4*)(lds + ((ku * 64 + erow) << 4)) = pk;
        }
    }

    // W preload (deferred until after encode; latency hidden under barrier)
    bf16x8 wb[2][4][2];
    #pragma unroll
    for (int p = 0; p < 2; ++p)
        #pragma unroll
        for (int cnp = 0; cnp < 4; ++cnp)
            #pragma unroll
            for (int s = 0; s < 2; ++s)
                wb[p][cnp][s] = W1FR(p, cnp, s);

    f32x16 acc[2][4];
    #pragma unroll
    for (int a = 0; a < 2; ++a)
        #pragma unroll
        for (int b = 0; b < 4; ++b) acc[a][b] = (f32x16)(0.0f);

    lds_barrier();   // feats visible; W prefetches stay in flight

    // ---------------- layer 1: K=640, 32x32x16, depth-2 W rotation ----------
    #pragma unroll
    for (int ks = 0; ks < NK1; ++ks) {
        const int cur = ks & 1;
        __builtin_amdgcn_s_setprio(1);
        #pragma unroll
        for (int s = 0; s < 2; ++s) {
            #pragma unroll
            for (int rn = 0; rn < 2; ++rn) {
                bf16x8 af = LDS_BF(ks, s, rn);
                #pragma unroll
                for (int cnp = 0; cnp < 4; ++cnp)
                    acc[rn][cnp] = __builtin_amdgcn_mfma_f32_32x32x16_bf16(
                        wb[cur][cnp][s], af, acc[rn][cnp], 0, 0, 0);
            }
        }
        __builtin_amdgcn_s_setprio(0);
        if (ks + 2 < NK1) {
            #pragma unroll
            for (int cnp = 0; cnp < 4; ++cnp)
                #pragma unroll
                for (int s = 0; s < 2; ++s)
                    wb[cur][cnp][s] = W1FR(ks + 2, cnp, s);
        } else {
            #pragma unroll
            for (int cnp = 0; cnp < 4; ++cnp)
                #pragma unroll
                for (int s = 0; s < 2; ++s)
                    wb[cur][cnp][s] = W2FR(ks + 2 - NK1, cnp, s);
        }
    }

    lds_barrier();   // all feats reads done; h may alias feats

    // ---------------- bias + leaky -> h (unit-major, contiguous 8B writes) -----
    #pragma unroll
    for (int rn = 0; rn < 2; ++rn) {
        const int row = rn * 32 + l31;
        #pragma unroll
        for (int cnp = 0; cnp < 4; ++cnp) {
            #pragma unroll
            for (int rg = 0; rg < 4; ++rg) {
                const int colb = wcol + cnp * 32 + rg * 8 + l32 * 4;
                const f32x4 bb = *(const f32x4*)(b1 + colb);
                float h0 = acc[rn][cnp][rg * 4 + 0] + bb[0];
                float h1 = acc[rn][cnp][rg * 4 + 1] + bb[1];
                float h2 = acc[rn][cnp][rg * 4 + 2] + bb[2];
                float h3 = acc[rn][cnp][rg * 4 + 3] + bb[3];
                h0 = (h0 >= 0.f) ? h0 : 0.01f * h0;
                h1 = (h1 >= 0.f) ? h1 : 0.01f * h1;
                h2 = (h2 >= 0.f) ? h2 : 0.01f * h2;
                h3 = (h3 >= 0.f) ? h3 : 0.01f * h3;
                u32x2 pk;
                pk.x = pk2(h0, h1);
                pk.y = pk2(h2, h3);
                const int ku = wave * 16 + cnp * 4 + rg;   // col/8
                *(u32x2*)(lds + ((ku * 64 + row) << 4) + l32 * 8) = pk;
            }
        }
    }

    #pragma unroll
    for (int a = 0; a < 2; ++a)
        #pragma unroll
        for (int b = 0; b < 4; ++b) acc[a][b] = (f32x16)(0.0f);

    lds_barrier();   // h visible

    // ---------------- layer 2: K=512 ----------------
    #pragma unroll
    for (int ks = 0; ks < NK2; ++ks) {
        const int cur = ks & 1;
        __builtin_amdgcn_s_setprio(1);
        #pragma unroll
        for (int s = 0; s < 2; ++s) {
            #pragma unroll
            for (int rn = 0; rn < 2; ++rn) {
                bf16x8 hf = LDS_BF(ks, s, rn);
                #pragma unroll
                for (int cnp = 0; cnp < 4; ++cnp)
                    acc[rn][cnp] = __builtin_amdgcn_mfma_f32_32x32x16_bf16(
                        wb[cur][cnp][s], hf, acc[rn][cnp], 0, 0, 0);
            }
        }
        __builtin_amdgcn_s_setprio(0);
        if (ks + 2 < NK2) {
            #pragma unroll
            for (int cnp = 0; cnp < 4; ++cnp)
                #pragma unroll
                for (int s = 0; s < 2; ++s)
                    wb[cur][cnp][s] = W2FR(ks + 2, cnp, s);
        }
    }

    // ---------------- epilogue: bias + float4 stores ----------------
    #pragma unroll
    for (int rn = 0; rn < 2; ++rn) {
        const int row = rowbase + rn * 32 + l31;
        #pragma unroll
        for (int cnp = 0; cnp < 4; ++cnp) {
            #pragma unroll
            for (int rg = 0; rg < 4; ++rg) {
                const int colb = wcol + cnp * 32 + rg * 8 + l32 * 4;
                const f32x4 bb = *(const f32x4*)(b2 + colb);
                f32x4 o;
                o.x = acc[rn][cnp][rg * 4 + 0] + bb[0];
                o.y = acc[rn][cnp][rg * 4 + 1] + bb[1];
                o.z = acc[rn][cnp][rg * 4 + 2] + bb[2];
                o.w = acc[rn][cnp][rg * 4 + 3] + bb[3];
                *(f32x4*)(out + row * 512 + colb) = o;
            }
        }
    }
}

extern "C" void kernel_launch(void* const* d_in, const int* in_sizes, int n_in,
                              void* d_out, int out_size, void* d_ws, size_t ws_size,
                              hipStream_t stream)
{
    (void)in_sizes; (void)n_in; (void)out_size; (void)ws_size;
    const float* pf  = (const float*)d_in[0];
    const float* pt  = (const float*)d_in[1];
    const float* nm  = (const float*)d_in[2];
    const float* Wsx = (const float*)d_in[3];
    const float* bsx = (const float*)d_in[4];
    const float* Wcx = (const float*)d_in[5];
    const float* bcx = (const float*)d_in[6];
    const float* Wsy = (const float*)d_in[7];
    const float* bsy = (const float*)d_in[8];
    const float* Wcy = (const float*)d_in[9];
    const float* bcy = (const float*)d_in[10];
    const float* Wn  = (const float*)d_in[11];
    const float* bn  = (const float*)d_in[12];
    const float* W1  = (const float*)d_in[13];
    const float* b1  = (const float*)d_in[14];
    const float* W2  = (const float*)d_in[15];
    const float* b2  = (const float*)d_in[16];

    unsigned char* ws = (unsigned char*)d_ws;
    unsigned short* w1bp = (unsigned short*)(ws);
    unsigned short* w2bp = (unsigned short*)(ws + 512 * 640 * 2);
    float* wf  = (float*)(ws + 512 * 640 * 2 + 512 * 512 * 2);
    float* bfv = (float*)(ws + 512 * 640 * 2 + 512 * 512 * 2 + 640 * 4);

    const int prep_threads = 512 * 640 + 512 * 512;
    prep_kernel<<<(prep_threads + 255) / 256, 256, 0, stream>>>(
        W1, W2, Wsx, bsx, Wcx, bcx, Wsy, bsy, Wcy, bcy, Wn, bn, w1bp, w2bp, wf, bfv);

    mlp_kernel<<<NROWS / BM, 256, 0, stream>>>(
        pf, pt, nm, w1bp, w2bp, wf, bfv, b1, b2, (float*)d_out);
}

// Round 21
// 175.854 us; speedup vs baseline: 1.3687x; 1.2246x over previous
//
#include <hip/hip_runtime.h>
#include <hip/hip_bf16.h>
#include <stdint.h>

#define NROWS 131072
#define BM 128
#define NK1 20
#define NK2 16
#define FSTR 1280
#define HSTR 1024

typedef __attribute__((ext_vector_type(8))) short bf16x8;
typedef __attribute__((ext_vector_type(4))) float f32x4;
typedef __attribute__((ext_vector_type(4))) int i32x4;
typedef __attribute__((ext_vector_type(2))) unsigned int u32x2;

__device__ __forceinline__ unsigned f2bf(float x) {
    union { float f; unsigned u; } v; v.f = x;
    unsigned r = v.u + 0x7FFFu + ((v.u >> 16) & 1u);
    return r >> 16;
}

__device__ __forceinline__ unsigned pk2(float a, float b) {
    float2 t; t.x = a; t.y = b;
    __hip_bfloat162 h = __float22bfloat162_rn(t);
    union { __hip_bfloat162 h; unsigned u; } c; c.h = h;
    return c.u;
}

// LDS-only barrier: order LDS writes->reads without draining vmcnt
// (in-flight W prefetches / stores keep flying across phase boundaries).
__device__ __forceinline__ void lds_barrier() {
    asm volatile("s_waitcnt lgkmcnt(0)" ::: "memory");
    __builtin_amdgcn_sched_barrier(0);
    __builtin_amdgcn_s_barrier();
}

// ws layout:
// [0, 655360)            W1 bf16 PACKED [wv8][ks20][cf4][lane64][8]
// [655360, 1179648)      W2 bf16 PACKED [wv8][ks16][cf4][lane64][8]
// [1179648, +2560)       wf[640] f32 (trig rows pre-scaled by 1/2pi)
// [1182208, +2560)       bfv[640] f32 (cos folded to sin, pre-scaled)

__global__ void prep_kernel(
    const float* __restrict__ W1, const float* __restrict__ W2,
    const float* __restrict__ Wsx, const float* __restrict__ bsx,
    const float* __restrict__ Wcx, const float* __restrict__ bcx,
    const float* __restrict__ Wsy, const float* __restrict__ bsy,
    const float* __restrict__ Wcy, const float* __restrict__ bcy,
    const float* __restrict__ Wn, const float* __restrict__ bn,
    unsigned short* __restrict__ w1bp, unsigned short* __restrict__ w2bp,
    float* __restrict__ wf, float* __restrict__ bfv)
{
    int i = blockIdx.x * blockDim.x + threadIdx.x;
    const int n1 = 512 * 640;
    const int n2 = 512 * 512;
    if (i < n1) {
        int e = i & 7, g = i >> 3;
        int lane = g & 63, cf = (g >> 6) & 3;
        int wk = g >> 8;                 // wv*20 + ks
        int ks = wk % 20, wv = wk / 20;
        int col = wv * 64 + cf * 16 + (lane & 15);
        int k   = ks * 32 + (lane >> 4) * 8 + e;
        w1bp[i] = (unsigned short)f2bf(W1[col * 640 + k]);
    } else if (i < n1 + n2) {
        int ii = i - n1;
        int e = ii & 7, g = ii >> 3;
        int lane = g & 63, cf = (g >> 6) & 3;
        int ks = (g >> 8) & 15, wv = g >> 12;
        int col = wv * 64 + cf * 16 + (lane & 15);
        int k   = ks * 32 + (lane >> 4) * 8 + e;
        w2bp[ii] = (unsigned short)f2bf(W2[col * 512 + k]);
    }
    if (i < 640) {
        const float HPI = 1.57079632679489662f;
        const float INV2PI = 0.15915494309189535f;
        float w, b;
        if (i < 512) {
            int j = i & 63, q = (i >> 6) & 3;
            if      (q == 0) { w = Wsx[j]; b = bsx[j]; }
            else if (q == 1) { w = Wcx[j]; b = bcx[j] + HPI; }
            else if (q == 2) { w = Wsy[j]; b = bsy[j]; }
            else             { w = Wcy[j]; b = bcy[j] + HPI; }
            w *= INV2PI; b *= INV2PI;    // revolutions for raw v_sin_f32
        } else { w = Wn[i - 512]; b = bn[i - 512]; }
        wf[i] = w; bfv[i] = b;
    }
}

// LDS: feats [128][640] bf16, stride 1280 B, byte-XOR ((row&15)<<4) = 163840 B
//      h     [128][512] bf16, stride 1024 B, same XOR (aliased)

__global__ __launch_bounds__(512, 2) void mlp_kernel(
    const float* __restrict__ pf, const float* __restrict__ pt,
    const float* __restrict__ nm,
    const unsigned short* __restrict__ w1bp,
    const unsigned short* __restrict__ w2bp,
    const float* __restrict__ wf, const float* __restrict__ bfv,
    const float* __restrict__ b1, const float* __restrict__ b2,
    float* __restrict__ out)
{
    __shared__ __align__(16) unsigned char lds[163840];

    const int tid  = threadIdx.x;
    const int lane = tid & 63;
    const int wave = tid >> 6;          // 0..7, each owns 64 output cols
    const int l15  = lane & 15;
    const int l4   = lane >> 4;         // 0..3
    const int rowbase = blockIdx.x * BM;
    const int wcol = wave * 64;
    const unsigned swz = (unsigned)(l15 << 4);

    // v-input loads issued FIRST (HBM latency overlaps W preload L2 latency)
    const int erow = tid >> 2;          // 0..127
    const int esub = tid & 3;
    const int grow = rowbase + erow;
    const float v0 = pf[grow * 2 + 0];
    const float v1 = pf[grow * 2 + 1];
    const float v2 = pt[grow * 2 + 0];
    const float v3 = pt[grow * 2 + 1];
    const float v4 = nm[grow];

    const unsigned short* w1p = w1bp + wave * (NK1 * 4 * 512) + lane * 8;
    const unsigned short* w2p = w2bp + wave * (NK2 * 4 * 512) + lane * 8;
#define W1FRAG(KS, CF) (*(const bf16x8*)(w1p + ((KS) * 4 + (CF)) * 512))
#define W2FRAG(KS, CF) (*(const bf16x8*)(w2p + ((KS) * 4 + (CF)) * 512))
#define LDS_AF(KS, RF) (*(const bf16x8*)(lds + ((RF) * 16 + l15) * FSTR + \
                        (((unsigned)((KS) * 64 + l4 * 16)) ^ swz)))
#define LDS_HF(KS, RF) (*(const bf16x8*)(lds + ((RF) * 16 + l15) * HSTR + \
                        (((unsigned)((KS) * 64 + l4 * 16)) ^ swz)))

    // depth-2 rotating W-fragment buffers
    bf16x8 wb[2][4];
    #pragma unroll
    for (int p = 0; p < 2; ++p)
        #pragma unroll
        for (int cf = 0; cf < 4; ++cf)
            wb[p][cf] = W1FRAG(p, cf);

    // ---------------- encode: 4 threads/row, k = esub*8 + j*32 ----------------
    {
        const unsigned eswz = (unsigned)((erow & 15) << 4);
        #pragma unroll
        for (int j = 0; j < 20; ++j) {
            const int k = esub * 8 + j * 32;
            const float xv = (j < 4) ? v0 : (j < 8) ? v1 :
                             (j < 12) ? v2 : (j < 16) ? v3 : v4;
            const f32x4 w0 = *(const f32x4*)(wf + k);
            const f32x4 w1v = *(const f32x4*)(wf + k + 4);
            const f32x4 c0 = *(const f32x4*)(bfv + k);
            const f32x4 c1 = *(const f32x4*)(bfv + k + 4);
            float r[8];
            #pragma unroll
            for (int t = 0; t < 4; ++t) {
                float a0 = fmaf(xv, w0[t], c0[t]);
                float a1 = fmaf(xv, w1v[t], c1[t]);
                if (j < 16) {
                    asm("v_sin_f32 %0, %1" : "=v"(r[t])     : "v"(a0));
                    asm("v_sin_f32 %0, %1" : "=v"(r[t + 4]) : "v"(a1));
                } else { r[t] = a0; r[t + 4] = a1; }
            }
            i32x4 pk;
            pk.x = (int)pk2(r[0], r[1]);
            pk.y = (int)pk2(r[2], r[3]);
            pk.z = (int)pk2(r[4], r[5]);
            pk.w = (int)pk2(r[6], r[7]);
            *(i32x4*)(lds + erow * FSTR + (((unsigned)(k * 2)) ^ eswz)) = pk;
        }
    }

    f32x4 acc[8][4];
    #pragma unroll
    for (int a = 0; a < 8; ++a)
        #pragma unroll
        for (int b = 0; b < 4; ++b) acc[a][b] = (f32x4)(0.0f);

    lds_barrier();   // feats visible; W prefetches stay in flight

    // ---------------- layer 1: K=640, depth-2 W rotation ----------------
    #pragma unroll
    for (int ks = 0; ks < NK1; ++ks) {
        const int cur = ks & 1;
        __builtin_amdgcn_s_setprio(1);
        #pragma unroll
        for (int rf = 0; rf < 8; ++rf) {
            bf16x8 af = LDS_AF(ks, rf);
            #pragma unroll
            for (int cf = 0; cf < 4; ++cf)
                acc[rf][cf] = __builtin_amdgcn_mfma_f32_16x16x32_bf16(
                    wb[cur][cf], af, acc[rf][cf], 0, 0, 0);
        }
        __builtin_amdgcn_s_setprio(0);
        if (ks + 2 < NK1) {
            #pragma unroll
            for (int cf = 0; cf < 4; ++cf) wb[cur][cf] = W1FRAG(ks + 2, cf);
        } else {
            #pragma unroll
            for (int cf = 0; cf < 4; ++cf) wb[cur][cf] = W2FRAG(ks + 2 - NK1, cf);
        }
    }

    lds_barrier();   // all feats reads done; h may alias feats

    // ---------------- bias + leaky -> h (bf16, 8B LDS writes) ----------------
    #pragma unroll
    for (int cf = 0; cf < 4; ++cf) {
        const int colb = wcol + cf * 16 + l4 * 4;
        const f32x4 bb = *(const f32x4*)(b1 + colb);
        #pragma unroll
        for (int rf = 0; rf < 8; ++rf) {
            const int row = rf * 16 + l15;
            float h0 = acc[rf][cf][0] + bb[0];
            float h1 = acc[rf][cf][1] + bb[1];
            float h2 = acc[rf][cf][2] + bb[2];
            float h3 = acc[rf][cf][3] + bb[3];
            h0 = (h0 >= 0.f) ? h0 : 0.01f * h0;
            h1 = (h1 >= 0.f) ? h1 : 0.01f * h1;
            h2 = (h2 >= 0.f) ? h2 : 0.01f * h2;
            h3 = (h3 >= 0.f) ? h3 : 0.01f * h3;
            u32x2 pk;
            pk.x = pk2(h0, h1);
            pk.y = pk2(h2, h3);
            *(u32x2*)(lds + row * HSTR + (((unsigned)(colb * 2)) ^ swz)) = pk;
        }
    }

    #pragma unroll
    for (int a = 0; a < 8; ++a)
        #pragma unroll
        for (int b = 0; b < 4; ++b) acc[a][b] = (f32x4)(0.0f);

    lds_barrier();   // h visible

    // ---------------- layer 2: K=512 ----------------
    #pragma unroll
    for (int ks = 0; ks < NK2; ++ks) {
        const int cur = ks & 1;
        __builtin_amdgcn_s_setprio(1);
        #pragma unroll
        for (int rf = 0; rf < 8; ++rf) {
            bf16x8 hf = LDS_HF(ks, rf);
            #pragma unroll
            for (int cf = 0; cf < 4; ++cf)
                acc[rf][cf] = __builtin_amdgcn_mfma_f32_16x16x32_bf16(
                    wb[cur][cf], hf, acc[rf][cf], 0, 0, 0);
        }
        __builtin_amdgcn_s_setprio(0);
        if (ks + 2 < NK2) {
            #pragma unroll
            for (int cf = 0; cf < 4; ++cf) wb[cur][cf] = W2FRAG(ks + 2, cf);
        }
    }

    // ---------------- epilogue: bias + float4 stores ----------------
    #pragma unroll
    for (int cf = 0; cf < 4; ++cf) {
        const int colb = wcol + cf * 16 + l4 * 4;
        const f32x4 bb = *(const f32x4*)(b2 + colb);
        #pragma unroll
        for (int rf = 0; rf < 8; ++rf) {
            const int row = rowbase + rf * 16 + l15;
            f32x4 o = acc[rf][cf] + bb;
            *(f32x4*)(out + row * 512 + colb) = o;
        }
    }
}

extern "C" void kernel_launch(void* const* d_in, const int* in_sizes, int n_in,
                              void* d_out, int out_size, void* d_ws, size_t ws_size,
                              hipStream_t stream)
{
    (void)in_sizes; (void)n_in; (void)out_size; (void)ws_size;
    const float* pf  = (const float*)d_in[0];
    const float* pt  = (const float*)d_in[1];
    const float* nm  = (const float*)d_in[2];
    const float* Wsx = (const float*)d_in[3];
    const float* bsx = (const float*)d_in[4];
    const float* Wcx = (const float*)d_in[5];
    const float* bcx = (const float*)d_in[6];
    const float* Wsy = (const float*)d_in[7];
    const float* bsy = (const float*)d_in[8];
    const float* Wcy = (const float*)d_in[9];
    const float* bcy = (const float*)d_in[10];
    const float* Wn  = (const float*)d_in[11];
    const float* bn  = (const float*)d_in[12];
    const float* W1  = (const float*)d_in[13];
    const float* b1  = (const float*)d_in[14];
    const float* W2  = (const float*)d_in[15];
    const float* b2  = (const float*)d_in[16];

    unsigned char* ws = (unsigned char*)d_ws;
    unsigned short* w1bp = (unsigned short*)(ws);
    unsigned short* w2bp = (unsigned short*)(ws + 512 * 640 * 2);
    float* wf  = (float*)(ws + 512 * 640 * 2 + 512 * 512 * 2);
    float* bfv = (float*)(ws + 512 * 640 * 2 + 512 * 512 * 2 + 640 * 4);

    const int prep_threads = 512 * 640 + 512 * 512;
    prep_kernel<<<(prep_threads + 255) / 256, 256, 0, stream>>>(
        W1, W2, Wsx, bsx, Wcx, bcx, Wsy, bsy, Wcy, bcy, Wn, bn, w1bp, w2bp, wf, bfv);

    mlp_kernel<<<NROWS / BM, 512, 0, stream>>>(
        pf, pt, nm, w1bp, w2bp, wf, bfv, b1, b2, (float*)d_out);
}